// Round 1
// baseline (636.396 us; speedup 1.0000x reference)
//
#include <hip/hip_runtime.h>
#include <cstddef>

// ---------- types / helpers ----------
typedef unsigned int u32;
typedef unsigned short u16;
typedef short v8s __attribute__((ext_vector_type(8)));
typedef float v4f __attribute__((ext_vector_type(4)));

#define N_ROWS 32768
#define DIM 1024
#define NHEAD 8
#define HD 128
#define KSEL 2048

static __device__ __forceinline__ u16 f2bf(float f) {
  u32 u = __float_as_uint(f);
  u32 r = (u + 0x7FFFu + ((u >> 16) & 1u)) >> 16;   // RNE
  return (u16)r;
}
static __device__ __forceinline__ float bf2f(u16 b) {
  return __uint_as_float(((u32)b) << 16);
}
static __device__ __forceinline__ u32 mono(float s) {  // order-preserving f32->u32
  u32 b = __float_as_uint(s);
  return (b & 0x80000000u) ? ~b : (b | 0x80000000u);
}

// ---------- 1. fused copy + score ----------
__global__ __launch_bounds__(256) void score_copy_kernel(
    const float* __restrict__ roi, const float* __restrict__ wsc,
    const float* __restrict__ bsc, float* __restrict__ out,
    float* __restrict__ scores) {
  const int w = threadIdx.x >> 6, lane = threadIdx.x & 63;
  const int row = blockIdx.x * 4 + w;
  const float4* r4 = (const float4*)(roi + (size_t)row * DIM);
  const float4* w4 = (const float4*)wsc;
  float4* o4 = (float4*)(out + (size_t)row * DIM);
  float sum = 0.f;
#pragma unroll
  for (int rep = 0; rep < 4; ++rep) {
    int i = rep * 64 + lane;
    float4 v = r4[i];
    float4 q = w4[i];
    sum += v.x * q.x + v.y * q.y + v.z * q.z + v.w * q.w;
    o4[i] = v;
  }
#pragma unroll
  for (int d = 1; d < 64; d <<= 1) sum += __shfl_xor(sum, d);
  if (lane == 0) scores[row] = sum + bsc[0];
}

// ---------- 2. f32 -> bf16 convert ----------
__global__ __launch_bounds__(256) void cvt_kernel(const float* __restrict__ src,
                                                  u16* __restrict__ dst, int n) {
  int i = (blockIdx.x * 256 + threadIdx.x) * 4;
  if (i < n) {
    float4 v = *(const float4*)(src + i);
    ushort4 o = make_ushort4(f2bf(v.x), f2bf(v.y), f2bf(v.z), f2bf(v.w));
    *(ushort4*)(dst + i) = o;
  }
}

// ---------- 3. single-block radix-select top-K ----------
__global__ __launch_bounds__(1024) void topk_kernel(const float* __restrict__ scores,
                                                    int* __restrict__ out_idx) {
  __shared__ u32 hist[256];
  __shared__ int sneed;
  __shared__ u32 sprefix;
  __shared__ int scan_gt[1024];
  __shared__ int scan_eq[1024];
  const int tid = threadIdx.x;
  if (tid == 0) { sneed = KSEL; sprefix = 0u; }
  for (int pass = 0; pass < 4; ++pass) {
    const int shift = 24 - pass * 8;
    if (tid < 256) hist[tid] = 0u;
    __syncthreads();
    const u32 prefmask = (pass == 0) ? 0u : (0xFFFFFFFFu << (shift + 8));
    const u32 pref = sprefix;
    for (int i = tid; i < N_ROWS; i += 1024) {
      u32 key = mono(scores[i]);
      if ((key & prefmask) == pref) atomicAdd(&hist[(key >> shift) & 255u], 1u);
    }
    __syncthreads();
    if (tid == 0) {
      int need = sneed;
      u32 cum = 0;
      int b = 255;
      for (; b > 0; --b) {
        if (cum + hist[b] >= (u32)need) break;
        cum += hist[b];
      }
      sneed = need - (int)cum;
      sprefix = pref | ((u32)b << shift);
    }
    __syncthreads();
  }
  const u32 T = sprefix;
  // stable compaction: thread t owns contiguous indices [t*32, t*32+32)
  const int base = tid * 32;
  int cgt = 0, ceq = 0;
  for (int j = 0; j < 32; ++j) {
    u32 key = mono(scores[base + j]);
    cgt += (key > T);
    ceq += (key == T);
  }
  scan_gt[tid] = cgt;
  scan_eq[tid] = ceq;
  __syncthreads();
  for (int off = 1; off < 1024; off <<= 1) {
    int a = (tid >= off) ? scan_gt[tid - off] : 0;
    int b = (tid >= off) ? scan_eq[tid - off] : 0;
    __syncthreads();
    scan_gt[tid] += a;
    scan_eq[tid] += b;
    __syncthreads();
  }
  const int gt_off = scan_gt[tid] - cgt;
  const int eq_off = scan_eq[tid] - ceq;
  const int total_gt = scan_gt[1023];
  int g = gt_off, e = eq_off;
  for (int j = 0; j < 32; ++j) {
    u32 key = mono(scores[base + j]);
    if (key > T) {
      out_idx[g++] = base + j;
    } else if (key == T) {
      if (total_gt + e < KSEL) out_idx[total_gt + e] = base + j;  // lowest-index ties, jax-style
      e++;
    }
  }
}

// ---------- 4. gather selected rows -> xo[:,1024:2048] (bf16) ----------
__global__ __launch_bounds__(256) void gather_kernel(const float* __restrict__ out,
                                                     const int* __restrict__ idx,
                                                     u16* __restrict__ xo) {
  const int j = blockIdx.x;
  const int row = idx[j];
  const int c = threadIdx.x * 4;
  float4 v = *(const float4*)(out + (size_t)row * DIM + c);
  ushort4 o = make_ushort4(f2bf(v.x), f2bf(v.y), f2bf(v.z), f2bf(v.w));
  *(ushort4*)(xo + (size_t)j * 2048 + 1024 + c) = o;
}

// ---------- 5. GEMM  C[M,N] = A[M,Kd] @ W[N,Kd]^T + bias ----------
// 64x64 tile / block of 256 (4 waves, each 16 rows x 64 cols). bf16 MFMA 16x16x32.
template <int OUTF32>
__global__ __launch_bounds__(256) void gemm_xwt_kernel(
    const u16* __restrict__ A, int lda, const u16* __restrict__ W, int ldw,
    const float* __restrict__ bias, void* __restrict__ Cout, int ldc, int Kd) {
  __shared__ __align__(16) u16 As[64][32];
  __shared__ __align__(16) u16 Bs[64][32];
  const int m0 = blockIdx.y * 64, n0 = blockIdx.x * 64;
  const int w = threadIdx.x >> 6, lane = threadIdx.x & 63;
  const int t = lane & 15, quad = lane >> 4;
  const int srow = threadIdx.x >> 2, skc = (threadIdx.x & 3) * 8;
  v4f acc[4];
#pragma unroll
  for (int i = 0; i < 4; ++i) acc[i] = (v4f){0.f, 0.f, 0.f, 0.f};
  for (int k0 = 0; k0 < Kd; k0 += 32) {
    __syncthreads();
    *(uint4*)&As[srow][skc] = *(const uint4*)&A[(size_t)(m0 + srow) * lda + k0 + skc];
    *(uint4*)&Bs[srow][skc] = *(const uint4*)&W[(size_t)(n0 + srow) * ldw + k0 + skc];
    __syncthreads();
    v8s af = *(const v8s*)&As[w * 16 + t][quad * 8];
#pragma unroll
    for (int nc = 0; nc < 4; ++nc) {
      v8s bf = *(const v8s*)&Bs[nc * 16 + t][quad * 8];
      acc[nc] = __builtin_amdgcn_mfma_f32_16x16x32_bf16(af, bf, acc[nc], 0, 0, 0);
    }
  }
#pragma unroll
  for (int nc = 0; nc < 4; ++nc) {
    const int col = n0 + nc * 16 + t;
    const float bv = bias[col];
#pragma unroll
    for (int r = 0; r < 4; ++r) {
      const int row = m0 + w * 16 + quad * 4 + r;
      float v = acc[nc][r] + bv;
      if (OUTF32)
        ((float*)Cout)[(size_t)row * ldc + col] = v;
      else
        ((u16*)Cout)[(size_t)row * ldc + col] = f2bf(v);
    }
  }
}

// ---------- 6. per-(row,head) reciprocal norms of q and k ----------
__global__ __launch_bounds__(256) void norms_kernel(const u16* __restrict__ qb,
                                                    const u16* __restrict__ kb,
                                                    float* __restrict__ rnq,
                                                    float* __restrict__ rnk) {
  const int w = threadIdx.x >> 6, lane = threadIdx.x & 63;
  int p = blockIdx.x * 4 + w;
  const u16* src;
  float* dst;
  if (p < NHEAD * KSEL) {
    src = qb;
    dst = rnq;
  } else {
    src = kb;
    dst = rnk;
    p -= NHEAD * KSEL;
  }
  const int h = p >> 11, m = p & 2047;
  u32 u = *(const u32*)&src[(size_t)m * DIM + h * HD + lane * 2];
  float a = bf2f((u16)(u & 0xffffu)), b = bf2f((u16)(u >> 16));
  float ss = a * a + b * b;
#pragma unroll
  for (int d = 1; d < 64; d <<= 1) ss += __shfl_xor(ss, d);
  if (lane == 0) dst[h * KSEL + m] = 1.0f / (sqrtf(ss) + 1e-6f);
}

// ---------- 7. fused attention (online softmax, sim-masked) ----------
// grid: 8 heads * 32 q-blocks of 64 rows; block 256 = 4 waves, wave = 16 q rows.
__global__ __launch_bounds__(256) void attn_kernel(
    const u16* __restrict__ qb, const u16* __restrict__ kb, const u16* __restrict__ vb,
    const float* __restrict__ rnq, const float* __restrict__ rnk,
    u16* __restrict__ xo) {
  const int h = blockIdx.x >> 5;
  const int q0 = (blockIdx.x & 31) * 64;
  const int w = threadIdx.x >> 6, lane = threadIdx.x & 63;
  const int t = lane & 15, quad = lane >> 4;
  const int m0 = q0 + w * 16;

  __shared__ __align__(16) u16 Ks[32][136];   // [key][hd], padded (+8) vs 16-way conflicts
  __shared__ __align__(16) u16 Vt[128][40];   // transposed V: [hd][key], padded
  __shared__ __align__(16) u16 Ps[4][16][40]; // per-wave P buffer, padded
  __shared__ float rks[32];

  v8s qf[4];
#pragma unroll
  for (int c = 0; c < 4; ++c)
    qf[c] = *(const v8s*)&qb[(size_t)(m0 + t) * DIM + h * HD + c * 32 + quad * 8];
  float rq[4];
#pragma unroll
  for (int r = 0; r < 4; ++r) rq[r] = rnq[h * KSEL + m0 + quad * 4 + r];

  float mi[4], li[4];
#pragma unroll
  for (int r = 0; r < 4; ++r) { mi[r] = -1e30f; li[r] = 0.f; }
  v4f o[8];
#pragma unroll
  for (int f = 0; f < 8; ++f) o[f] = (v4f){0.f, 0.f, 0.f, 0.f};

  const float inv_sqrt_hd = 0.08838834764831845f;  // 1/sqrt(128)

  for (int kt = 0; kt < KSEL; kt += 32) {
    __syncthreads();
    for (int cc = threadIdx.x; cc < 512; cc += 256) {
      const int key = cc >> 4, hc = (cc & 15) * 8;
      *(uint4*)&Ks[key][hc] = *(const uint4*)&kb[(size_t)(kt + key) * DIM + h * HD + hc];
      uint4 vv = *(const uint4*)&vb[(size_t)(kt + key) * DIM + h * HD + hc];
      const u16* pv = (const u16*)&vv;
#pragma unroll
      for (int j = 0; j < 8; ++j) Vt[hc + j][key] = pv[j];
    }
    if (threadIdx.x < 32) rks[threadIdx.x] = rnk[h * KSEL + kt + threadIdx.x];
    __syncthreads();

    // S = q . k  (shared by logits and cosine-sim)
    v4f s0 = (v4f){0.f, 0.f, 0.f, 0.f}, s1 = (v4f){0.f, 0.f, 0.f, 0.f};
#pragma unroll
    for (int c = 0; c < 4; ++c) {
      v8s k0f = *(const v8s*)&Ks[t][c * 32 + quad * 8];
      v8s k1f = *(const v8s*)&Ks[16 + t][c * 32 + quad * 8];
      s0 = __builtin_amdgcn_mfma_f32_16x16x32_bf16(qf[c], k0f, s0, 0, 0, 0);
      s1 = __builtin_amdgcn_mfma_f32_16x16x32_bf16(qf[c], k1f, s1, 0, 0, 0);
    }
    const float rk0 = rks[t], rk1 = rks[16 + t];
#pragma unroll
    for (int r = 0; r < 4; ++r) {
      const float S0 = s0[r], S1 = s1[r];
      const float sim0 = S0 * rq[r] * rk0;
      const float sim1 = S1 * rq[r] * rk1;
      float l0 = (sim0 > 0.9f) ? S0 * inv_sqrt_hd : -10000.0f;
      float l1 = (sim1 > 0.9f) ? S1 * inv_sqrt_hd : -10000.0f;
      float tm = fmaxf(l0, l1);
      tm = fmaxf(tm, __shfl_xor(tm, 1));
      tm = fmaxf(tm, __shfl_xor(tm, 2));
      tm = fmaxf(tm, __shfl_xor(tm, 4));
      tm = fmaxf(tm, __shfl_xor(tm, 8));
      const float nm = fmaxf(mi[r], tm);
      const float al = expf(mi[r] - nm);
      const float p0 = expf(l0 - nm), p1 = expf(l1 - nm);
      float ps = p0 + p1;
      ps += __shfl_xor(ps, 1);
      ps += __shfl_xor(ps, 2);
      ps += __shfl_xor(ps, 4);
      ps += __shfl_xor(ps, 8);
      li[r] = li[r] * al + ps;
      mi[r] = nm;
#pragma unroll
      for (int f = 0; f < 8; ++f) o[f][r] *= al;
      Ps[w][quad * 4 + r][t] = f2bf(p0);
      Ps[w][quad * 4 + r][16 + t] = f2bf(p1);
    }
    __syncthreads();
    v8s pf = *(const v8s*)&Ps[w][t][quad * 8];
#pragma unroll
    for (int f = 0; f < 8; ++f) {
      v8s vf = *(const v8s*)&Vt[f * 16 + t][quad * 8];
      o[f] = __builtin_amdgcn_mfma_f32_16x16x32_bf16(pf, vf, o[f], 0, 0, 0);
    }
  }
  float inv[4];
#pragma unroll
  for (int r = 0; r < 4; ++r) inv[r] = (mi[r] > -9999.0f) ? 1.0f / li[r] : 0.0f;
#pragma unroll
  for (int f = 0; f < 8; ++f)
#pragma unroll
    for (int r = 0; r < 4; ++r)
      xo[(size_t)(m0 + quad * 4 + r) * 2048 + h * HD + f * 16 + t] = f2bf(o[f][r] * inv[r]);
}

// ---------- 8. final scatter: out[idx[j]] = 0.5*sel + 0.5*fused ----------
__global__ __launch_bounds__(256) void final_kernel(float* __restrict__ out,
                                                    const int* __restrict__ idx,
                                                    const float* __restrict__ fused) {
  const int j = blockIdx.x;
  const int row = idx[j];
  const int c = threadIdx.x * 4;
  float4 a = *(const float4*)(out + (size_t)row * DIM + c);
  float4 f = *(const float4*)(fused + (size_t)j * DIM + c);
  float4 rv;
  rv.x = 0.5f * (a.x + f.x);
  rv.y = 0.5f * (a.y + f.y);
  rv.z = 0.5f * (a.z + f.z);
  rv.w = 0.5f * (a.w + f.w);
  *(float4*)(out + (size_t)row * DIM + c) = rv;
}

// ---------- launch ----------
extern "C" void kernel_launch(void* const* d_in, const int* in_sizes, int n_in,
                              void* d_out, int out_size, void* d_ws, size_t ws_size,
                              hipStream_t stream) {
  const float* roi = (const float*)d_in[0];
  const float* w_score = (const float*)d_in[1];
  const float* b_score = (const float*)d_in[2];
  const float* wq = (const float*)d_in[3];
  const float* bq = (const float*)d_in[4];
  const float* wk = (const float*)d_in[5];
  const float* bk = (const float*)d_in[6];
  const float* wv = (const float*)d_in[7];
  const float* bv = (const float*)d_in[8];
  const float* wo = (const float*)d_in[9];
  const float* bo = (const float*)d_in[10];
  float* out = (float*)d_out;

  char* p = (char*)d_ws;
  auto alloc = [&](size_t bytes) {
    char* r = p;
    p += (bytes + 255) & ~(size_t)255;
    return r;
  };
  float* scores = (float*)alloc((size_t)N_ROWS * 4);
  int* topk = (int*)alloc((size_t)KSEL * 4);
  u16* wqb = (u16*)alloc((size_t)DIM * DIM * 2);
  u16* wkb = (u16*)alloc((size_t)DIM * DIM * 2);
  u16* wvb = (u16*)alloc((size_t)DIM * DIM * 2);
  u16* wob = (u16*)alloc((size_t)DIM * 2 * DIM * 2);
  u16* xo = (u16*)alloc((size_t)KSEL * 2048 * 2);  // [agg | dst] bf16
  u16* qbuf = (u16*)alloc((size_t)KSEL * DIM * 2);
  u16* kbuf = (u16*)alloc((size_t)KSEL * DIM * 2);
  u16* vbuf = (u16*)alloc((size_t)KSEL * DIM * 2);
  float* rnq = (float*)alloc((size_t)NHEAD * KSEL * 4);
  float* rnk = (float*)alloc((size_t)NHEAD * KSEL * 4);
  float* fused = (float*)alloc((size_t)KSEL * DIM * 4);

  score_copy_kernel<<<N_ROWS / 4, 256, 0, stream>>>(roi, w_score, b_score, out, scores);
  cvt_kernel<<<DIM * DIM / 1024, 256, 0, stream>>>(wq, wqb, DIM * DIM);
  cvt_kernel<<<DIM * DIM / 1024, 256, 0, stream>>>(wk, wkb, DIM * DIM);
  cvt_kernel<<<DIM * DIM / 1024, 256, 0, stream>>>(wv, wvb, DIM * DIM);
  cvt_kernel<<<DIM * 2 * DIM / 1024, 256, 0, stream>>>(wo, wob, DIM * 2 * DIM);
  topk_kernel<<<1, 1024, 0, stream>>>(scores, topk);
  gather_kernel<<<KSEL, 256, 0, stream>>>(out, topk, xo);
  gemm_xwt_kernel<0><<<dim3(16, 32), 256, 0, stream>>>(xo + 1024, 2048, wqb, DIM, bq, qbuf, DIM, DIM);
  gemm_xwt_kernel<0><<<dim3(16, 32), 256, 0, stream>>>(xo + 1024, 2048, wkb, DIM, bk, kbuf, DIM, DIM);
  gemm_xwt_kernel<0><<<dim3(16, 32), 256, 0, stream>>>(xo + 1024, 2048, wvb, DIM, bv, vbuf, DIM, DIM);
  norms_kernel<<<2 * NHEAD * KSEL / 4 / 64, 256, 0, stream>>>(qbuf, kbuf, rnq, rnk);
  attn_kernel<<<NHEAD * 32, 256, 0, stream>>>(qbuf, kbuf, vbuf, rnq, rnk, xo);
  gemm_xwt_kernel<1><<<dim3(16, 32), 256, 0, stream>>>(xo, 2048, wob, 2048, bo, fused, DIM, 2048);
  final_kernel<<<KSEL, 256, 0, stream>>>(out, topk, fused);
}

// Round 2
// 496.165 us; speedup vs baseline: 1.2826x; 1.2826x over previous
//
#include <hip/hip_runtime.h>
#include <cstddef>

// ---------- types / helpers ----------
typedef unsigned int u32;
typedef unsigned short u16;
typedef short v8s __attribute__((ext_vector_type(8)));
typedef float v4f __attribute__((ext_vector_type(4)));

#define N_ROWS 32768
#define DIM 1024
#define NHEAD 8
#define HD 128
#define KSEL 2048

static __device__ __forceinline__ u16 f2bf(float f) {
  u32 u = __float_as_uint(f);
  u32 r = (u + 0x7FFFu + ((u >> 16) & 1u)) >> 16;   // RNE
  return (u16)r;
}
static __device__ __forceinline__ float bf2f(u16 b) {
  return __uint_as_float(((u32)b) << 16);
}
static __device__ __forceinline__ u32 mono(float s) {  // order-preserving f32->u32
  u32 b = __float_as_uint(s);
  return (b & 0x80000000u) ? ~b : (b | 0x80000000u);
}

// ---------- 1. fused copy + score ----------
__global__ __launch_bounds__(256) void score_copy_kernel(
    const float* __restrict__ roi, const float* __restrict__ wsc,
    const float* __restrict__ bsc, float* __restrict__ out,
    float* __restrict__ scores) {
  const int w = threadIdx.x >> 6, lane = threadIdx.x & 63;
  const int row = blockIdx.x * 4 + w;
  const float4* r4 = (const float4*)(roi + (size_t)row * DIM);
  const float4* w4 = (const float4*)wsc;
  float4* o4 = (float4*)(out + (size_t)row * DIM);
  float sum = 0.f;
#pragma unroll
  for (int rep = 0; rep < 4; ++rep) {
    int i = rep * 64 + lane;
    float4 v = r4[i];
    float4 q = w4[i];
    sum += v.x * q.x + v.y * q.y + v.z * q.z + v.w * q.w;
    o4[i] = v;
  }
#pragma unroll
  for (int d = 1; d < 64; d <<= 1) sum += __shfl_xor(sum, d);
  if (lane == 0) scores[row] = sum + bsc[0];
}

// ---------- 2. f32 -> bf16 convert (all four weights in one launch) ----------
__global__ __launch_bounds__(256) void cvt4_kernel(
    const float* __restrict__ wq, const float* __restrict__ wk,
    const float* __restrict__ wv, const float* __restrict__ wo,
    u16* __restrict__ wqb, u16* __restrict__ wkb,
    u16* __restrict__ wvb, u16* __restrict__ wob) {
  const int M = DIM * DIM;  // 1M elements per QKV weight
  long long i = ((long long)blockIdx.x * 256 + threadIdx.x) * 4;
  const float* src;
  u16* dst;
  if (i < M) {
    src = wq; dst = wqb;
  } else if (i < 2LL * M) {
    src = wk; dst = wkb; i -= M;
  } else if (i < 3LL * M) {
    src = wv; dst = wvb; i -= 2LL * M;
  } else {
    src = wo; dst = wob; i -= 3LL * M;
  }
  float4 v = *(const float4*)(src + i);
  ushort4 o = make_ushort4(f2bf(v.x), f2bf(v.y), f2bf(v.z), f2bf(v.w));
  *(ushort4*)(dst + i) = o;
}

// ---------- 3. single-block radix-select top-K ----------
__global__ __launch_bounds__(1024) void topk_kernel(const float* __restrict__ scores,
                                                    int* __restrict__ out_idx) {
  __shared__ u32 hist[256];
  __shared__ int sneed;
  __shared__ u32 sprefix;
  __shared__ int scan_gt[1024];
  __shared__ int scan_eq[1024];
  const int tid = threadIdx.x;
  if (tid == 0) { sneed = KSEL; sprefix = 0u; }
  for (int pass = 0; pass < 4; ++pass) {
    const int shift = 24 - pass * 8;
    if (tid < 256) hist[tid] = 0u;
    __syncthreads();
    const u32 prefmask = (pass == 0) ? 0u : (0xFFFFFFFFu << (shift + 8));
    const u32 pref = sprefix;
    for (int i = tid; i < N_ROWS; i += 1024) {
      u32 key = mono(scores[i]);
      if ((key & prefmask) == pref) atomicAdd(&hist[(key >> shift) & 255u], 1u);
    }
    __syncthreads();
    if (tid == 0) {
      int need = sneed;
      u32 cum = 0;
      int b = 255;
      for (; b > 0; --b) {
        if (cum + hist[b] >= (u32)need) break;
        cum += hist[b];
      }
      sneed = need - (int)cum;
      sprefix = pref | ((u32)b << shift);
    }
    __syncthreads();
  }
  const u32 T = sprefix;
  // stable compaction: thread t owns contiguous indices [t*32, t*32+32)
  const int base = tid * 32;
  int cgt = 0, ceq = 0;
  for (int j = 0; j < 32; ++j) {
    u32 key = mono(scores[base + j]);
    cgt += (key > T);
    ceq += (key == T);
  }
  scan_gt[tid] = cgt;
  scan_eq[tid] = ceq;
  __syncthreads();
  for (int off = 1; off < 1024; off <<= 1) {
    int a = (tid >= off) ? scan_gt[tid - off] : 0;
    int b = (tid >= off) ? scan_eq[tid - off] : 0;
    __syncthreads();
    scan_gt[tid] += a;
    scan_eq[tid] += b;
    __syncthreads();
  }
  const int gt_off = scan_gt[tid] - cgt;
  const int eq_off = scan_eq[tid] - ceq;
  const int total_gt = scan_gt[1023];
  int g = gt_off, e = eq_off;
  for (int j = 0; j < 32; ++j) {
    u32 key = mono(scores[base + j]);
    if (key > T) {
      out_idx[g++] = base + j;
    } else if (key == T) {
      if (total_gt + e < KSEL) out_idx[total_gt + e] = base + j;  // lowest-index ties, jax-style
      e++;
    }
  }
}

// ---------- 4. gather selected rows -> xo[:,1024:2048] (bf16) ----------
__global__ __launch_bounds__(256) void gather_kernel(const float* __restrict__ out,
                                                     const int* __restrict__ idx,
                                                     u16* __restrict__ xo) {
  const int j = blockIdx.x;
  const int row = idx[j];
  const int c = threadIdx.x * 4;
  float4 v = *(const float4*)(out + (size_t)row * DIM + c);
  ushort4 o = make_ushort4(f2bf(v.x), f2bf(v.y), f2bf(v.z), f2bf(v.w));
  *(ushort4*)(xo + (size_t)j * 2048 + 1024 + c) = o;
}

// ---------- 5. GEMM  C[M,N] = A[M,Kd] @ W[N,Kd]^T + bias ----------
// 64x64 tile / block of 256 (4 waves, each 16 rows x 64 cols). bf16 MFMA 16x16x32.
// OUT_MODE: 0 = bf16 row-major, 1 = f32 row-major, 2 = bf16 transposed head-planar [h][hd][key]
template <int OUT_MODE>
__global__ __launch_bounds__(256) void gemm_xwt_kernel(
    const u16* __restrict__ A, int lda, const u16* __restrict__ W, int ldw,
    const float* __restrict__ bias, void* __restrict__ Cout, int ldc, int Kd) {
  __shared__ __align__(16) u16 As[64][40];  // +8 pad: ds_read_b128 2-way only
  __shared__ __align__(16) u16 Bs[64][40];
  const int m0 = blockIdx.y * 64, n0 = blockIdx.x * 64;
  const int w = threadIdx.x >> 6, lane = threadIdx.x & 63;
  const int t = lane & 15, quad = lane >> 4;
  const int srow = threadIdx.x >> 2, skc = (threadIdx.x & 3) * 8;
  v4f acc[4];
#pragma unroll
  for (int i = 0; i < 4; ++i) acc[i] = (v4f){0.f, 0.f, 0.f, 0.f};
  const u16* aptr = A + (size_t)(m0 + srow) * lda + skc;
  const u16* bptr = W + (size_t)(n0 + srow) * ldw + skc;
  uint4 areg = *(const uint4*)aptr;
  uint4 breg = *(const uint4*)bptr;
  for (int k0 = 0; k0 < Kd; k0 += 32) {
    __syncthreads();
    *(uint4*)&As[srow][skc] = areg;
    *(uint4*)&Bs[srow][skc] = breg;
    __syncthreads();
    const int kn = (k0 + 32 < Kd) ? k0 + 32 : 0;  // wrap: harmless reload, keeps loads uniform
    areg = *(const uint4*)(aptr + kn);
    breg = *(const uint4*)(bptr + kn);
    v8s af = *(const v8s*)&As[w * 16 + t][quad * 8];
#pragma unroll
    for (int nc = 0; nc < 4; ++nc) {
      v8s bf = *(const v8s*)&Bs[nc * 16 + t][quad * 8];
      acc[nc] = __builtin_amdgcn_mfma_f32_16x16x32_bf16(af, bf, acc[nc], 0, 0, 0);
    }
  }
#pragma unroll
  for (int nc = 0; nc < 4; ++nc) {
    const int col = n0 + nc * 16 + t;
    const float bv = bias[col];
    if (OUT_MODE == 2) {
      const int h = col >> 7, hd = col & 127;
      const int row0 = m0 + w * 16 + quad * 4;
      ushort4 pk = make_ushort4(f2bf(acc[nc][0] + bv), f2bf(acc[nc][1] + bv),
                                f2bf(acc[nc][2] + bv), f2bf(acc[nc][3] + bv));
      *(ushort4*)((u16*)Cout + (size_t)h * (HD * KSEL) + (size_t)hd * KSEL + row0) = pk;
    } else {
#pragma unroll
      for (int r = 0; r < 4; ++r) {
        const int row = m0 + w * 16 + quad * 4 + r;
        float v = acc[nc][r] + bv;
        if (OUT_MODE == 1)
          ((float*)Cout)[(size_t)row * ldc + col] = v;
        else
          ((u16*)Cout)[(size_t)row * ldc + col] = f2bf(v);
      }
    }
  }
}

// ---------- 6. per-(row,head) reciprocal norms of q and k ----------
__global__ __launch_bounds__(256) void norms_kernel(const u16* __restrict__ qb,
                                                    const u16* __restrict__ kb,
                                                    float* __restrict__ rnq,
                                                    float* __restrict__ rnk) {
  const int w = threadIdx.x >> 6, lane = threadIdx.x & 63;
  int p = blockIdx.x * 4 + w;
  const u16* src;
  float* dst;
  if (p < NHEAD * KSEL) {
    src = qb;
    dst = rnq;
  } else {
    src = kb;
    dst = rnk;
    p -= NHEAD * KSEL;
  }
  const int h = p >> 11, m = p & 2047;
  u32 u = *(const u32*)&src[(size_t)m * DIM + h * HD + lane * 2];
  float a = bf2f((u16)(u & 0xffffu)), b = bf2f((u16)(u >> 16));
  float ss = a * a + b * b;
#pragma unroll
  for (int d = 1; d < 64; d <<= 1) ss += __shfl_xor(ss, d);
  if (lane == 0) dst[h * KSEL + m] = 1.0f / (sqrtf(ss) + 1e-6f);
}

// ---------- 7. fused attention (static-max masked softmax) ----------
// grid: 8 heads * 32 q-blocks of 64 rows; block 256 = 4 waves, wave = 16 q rows.
// V supplied pre-transposed head-planar: vt[h][hd][key].
__global__ __launch_bounds__(256) void attn_kernel(
    const u16* __restrict__ qb, const u16* __restrict__ kb, const u16* __restrict__ vt,
    const float* __restrict__ rnq, const float* __restrict__ rnk,
    u16* __restrict__ xo) {
  const int h = blockIdx.x >> 5;
  const int q0 = (blockIdx.x & 31) * 64;
  const int tid = threadIdx.x;
  const int w = tid >> 6, lane = tid & 63;
  const int t = lane & 15, quad = lane >> 4;
  const int m0 = q0 + w * 16;

  __shared__ __align__(16) u16 Ks[32][136];   // [key][hd]
  __shared__ __align__(16) u16 Vs[128][40];   // [hd][key] (already transposed in global)
  __shared__ __align__(16) u16 Ps[4][16][40]; // per-wave P buffer
  __shared__ float rks[32];

  v8s qf[4];
#pragma unroll
  for (int c = 0; c < 4; ++c)
    qf[c] = *(const v8s*)&qb[(size_t)(m0 + t) * DIM + h * HD + c * 32 + quad * 8];
  float rq[4];
#pragma unroll
  for (int r = 0; r < 4; ++r) rq[r] = rnq[h * KSEL + m0 + quad * 4 + r];

  float li[4] = {0.f, 0.f, 0.f, 0.f};
  v4f o[8];
#pragma unroll
  for (int f = 0; f < 8; ++f) o[f] = (v4f){0.f, 0.f, 0.f, 0.f};

  const float scale = 0.08838834764831845f;  // 1/sqrt(128)

  // staging geometry
  const int kkey = tid >> 4;            // 0..15
  const int khc = (tid & 15) * 8;       // 0..120
  const int vhd = tid >> 2;             // 0..63
  const int vch = (tid & 3) * 8;        // 0..24
  const u16* kbase = kb + (size_t)h * HD + khc;
  const u16* vbase = vt + (size_t)h * (HD * KSEL) + (size_t)vhd * KSEL + vch;
  const float* rkb = rnk + h * KSEL + tid;

  uint4 kreg0, kreg1, vreg0, vreg1;
  float rkreg = 0.f;
#define PREFETCH(KT)                                                   \
  do {                                                                 \
    kreg0 = *(const uint4*)(kbase + (size_t)((KT) + kkey) * DIM);      \
    kreg1 = *(const uint4*)(kbase + (size_t)((KT) + kkey + 16) * DIM); \
    vreg0 = *(const uint4*)(vbase + (KT));                             \
    vreg1 = *(const uint4*)(vbase + (size_t)64 * KSEL + (KT));         \
    if (tid < 32) rkreg = rkb[(KT)];                                   \
  } while (0)

  PREFETCH(0);
  for (int kt = 0; kt < KSEL; kt += 32) {
    __syncthreads();
    *(uint4*)&Ks[kkey][khc] = kreg0;
    *(uint4*)&Ks[kkey + 16][khc] = kreg1;
    *(uint4*)&Vs[vhd][vch] = vreg0;
    *(uint4*)&Vs[vhd + 64][vch] = vreg1;
    if (tid < 32) rks[tid] = rkreg;
    __syncthreads();
    const int ktn = (kt + 32 < KSEL) ? kt + 32 : 0;
    PREFETCH(ktn);

    // S = q . k  (shared by logits and cosine-sim)
    v4f s0 = (v4f){0.f, 0.f, 0.f, 0.f}, s1 = (v4f){0.f, 0.f, 0.f, 0.f};
#pragma unroll
    for (int c = 0; c < 4; ++c) {
      v8s k0f = *(const v8s*)&Ks[t][c * 32 + quad * 8];
      v8s k1f = *(const v8s*)&Ks[16 + t][c * 32 + quad * 8];
      s0 = __builtin_amdgcn_mfma_f32_16x16x32_bf16(qf[c], k0f, s0, 0, 0, 0);
      s1 = __builtin_amdgcn_mfma_f32_16x16x32_bf16(qf[c], k1f, s1, 0, 0, 0);
    }
    const float rk0 = rks[t], rk1 = rks[16 + t];
#pragma unroll
    for (int r = 0; r < 4; ++r) {
      const float S0 = s0[r], S1 = s1[r];
      // valid => sim>0.9 => S>0 => p>=1; masked p underflows to exactly 0 at exp(-1e4)
      const float p0 = (S0 * rq[r] * rk0 > 0.9f) ? __expf(S0 * scale) : 0.f;
      const float p1 = (S1 * rq[r] * rk1 > 0.9f) ? __expf(S1 * scale) : 0.f;
      li[r] += p0 + p1;  // per-lane partial; reduced over t-lanes once at the end
      Ps[w][quad * 4 + r][t] = f2bf(p0);
      Ps[w][quad * 4 + r][16 + t] = f2bf(p1);
    }
    // per-wave LDS roundtrip (C-layout -> A-layout); DS ops in-order within a wave
    v8s pf = *(const v8s*)&Ps[w][t][quad * 8];
#pragma unroll
    for (int f = 0; f < 8; ++f) {
      v8s vf = *(const v8s*)&Vs[f * 16 + t][quad * 8];
      o[f] = __builtin_amdgcn_mfma_f32_16x16x32_bf16(pf, vf, o[f], 0, 0, 0);
    }
  }
#undef PREFETCH
  float inv[4];
#pragma unroll
  for (int r = 0; r < 4; ++r) {
    float l = li[r];
    l += __shfl_xor(l, 1);
    l += __shfl_xor(l, 2);
    l += __shfl_xor(l, 4);
    l += __shfl_xor(l, 8);
    inv[r] = (l > 0.f) ? 1.0f / l : 0.f;  // l==0 <=> no match (dropout-to-zero path)
  }
#pragma unroll
  for (int f = 0; f < 8; ++f)
#pragma unroll
    for (int r = 0; r < 4; ++r)
      xo[(size_t)(m0 + quad * 4 + r) * 2048 + h * HD + f * 16 + t] = f2bf(o[f][r] * inv[r]);
}

// ---------- 8. final scatter: out[idx[j]] = 0.5*sel + 0.5*fused ----------
__global__ __launch_bounds__(256) void final_kernel(float* __restrict__ out,
                                                    const int* __restrict__ idx,
                                                    const float* __restrict__ fused) {
  const int j = blockIdx.x;
  const int row = idx[j];
  const int c = threadIdx.x * 4;
  float4 a = *(const float4*)(out + (size_t)row * DIM + c);
  float4 f = *(const float4*)(fused + (size_t)j * DIM + c);
  float4 rv;
  rv.x = 0.5f * (a.x + f.x);
  rv.y = 0.5f * (a.y + f.y);
  rv.z = 0.5f * (a.z + f.z);
  rv.w = 0.5f * (a.w + f.w);
  *(float4*)(out + (size_t)row * DIM + c) = rv;
}

// ---------- launch ----------
extern "C" void kernel_launch(void* const* d_in, const int* in_sizes, int n_in,
                              void* d_out, int out_size, void* d_ws, size_t ws_size,
                              hipStream_t stream) {
  const float* roi = (const float*)d_in[0];
  const float* w_score = (const float*)d_in[1];
  const float* b_score = (const float*)d_in[2];
  const float* wq = (const float*)d_in[3];
  const float* bq = (const float*)d_in[4];
  const float* wk = (const float*)d_in[5];
  const float* bk = (const float*)d_in[6];
  const float* wv = (const float*)d_in[7];
  const float* bv = (const float*)d_in[8];
  const float* wo = (const float*)d_in[9];
  const float* bo = (const float*)d_in[10];
  float* out = (float*)d_out;

  char* p = (char*)d_ws;
  auto alloc = [&](size_t bytes) {
    char* r = p;
    p += (bytes + 255) & ~(size_t)255;
    return r;
  };
  float* scores = (float*)alloc((size_t)N_ROWS * 4);
  int* topk = (int*)alloc((size_t)KSEL * 4);
  u16* wqb = (u16*)alloc((size_t)DIM * DIM * 2);
  u16* wkb = (u16*)alloc((size_t)DIM * DIM * 2);
  u16* wvb = (u16*)alloc((size_t)DIM * DIM * 2);
  u16* wob = (u16*)alloc((size_t)DIM * 2 * DIM * 2);
  u16* xo = (u16*)alloc((size_t)KSEL * 2048 * 2);  // [agg | dst] bf16
  u16* qbuf = (u16*)alloc((size_t)KSEL * DIM * 2);
  u16* kbuf = (u16*)alloc((size_t)KSEL * DIM * 2);
  u16* vtbuf = (u16*)alloc((size_t)KSEL * DIM * 2);  // [h][hd][key]
  float* rnq = (float*)alloc((size_t)NHEAD * KSEL * 4);
  float* rnk = (float*)alloc((size_t)NHEAD * KSEL * 4);
  float* fused = (float*)alloc((size_t)KSEL * DIM * 4);

  score_copy_kernel<<<N_ROWS / 4, 256, 0, stream>>>(roi, w_score, b_score, out, scores);
  cvt4_kernel<<<5 * DIM * DIM / 1024, 256, 0, stream>>>(wq, wk, wv, wo, wqb, wkb, wvb, wob);
  topk_kernel<<<1, 1024, 0, stream>>>(scores, topk);
  gather_kernel<<<KSEL, 256, 0, stream>>>(out, topk, xo);
  gemm_xwt_kernel<0><<<dim3(16, 32), 256, 0, stream>>>(xo + 1024, 2048, wqb, DIM, bq, qbuf, DIM, DIM);
  gemm_xwt_kernel<0><<<dim3(16, 32), 256, 0, stream>>>(xo + 1024, 2048, wkb, DIM, bk, kbuf, DIM, DIM);
  gemm_xwt_kernel<2><<<dim3(16, 32), 256, 0, stream>>>(xo + 1024, 2048, wvb, DIM, bv, vtbuf, DIM, DIM);
  norms_kernel<<<2 * NHEAD * KSEL / 4, 256, 0, stream>>>(qbuf, kbuf, rnq, rnk);
  attn_kernel<<<NHEAD * 32, 256, 0, stream>>>(qbuf, kbuf, vtbuf, rnq, rnk, xo);
  gemm_xwt_kernel<1><<<dim3(16, 32), 256, 0, stream>>>(xo, 2048, wob, 2048, bo, fused, DIM, 2048);
  final_kernel<<<KSEL, 256, 0, stream>>>(out, topk, fused);
}

// Round 3
// 436.520 us; speedup vs baseline: 1.4579x; 1.1366x over previous
//
#include <hip/hip_runtime.h>
#include <cstddef>

// ---------- types / helpers ----------
typedef unsigned int u32;
typedef unsigned short u16;
typedef short v8s __attribute__((ext_vector_type(8)));
typedef float v4f __attribute__((ext_vector_type(4)));

#define N_ROWS 32768
#define DIM 1024
#define NHEAD 8
#define HD 128
#define KSEL 2048

static __device__ __forceinline__ u16 f2bf(float f) {
  u32 u = __float_as_uint(f);
  u32 r = (u + 0x7FFFu + ((u >> 16) & 1u)) >> 16;   // RNE
  return (u16)r;
}
static __device__ __forceinline__ float bf2f(u16 b) {
  return __uint_as_float(((u32)b) << 16);
}
static __device__ __forceinline__ u32 mono(float s) {  // order-preserving f32->u32
  u32 b = __float_as_uint(s);
  return (b & 0x80000000u) ? ~b : (b | 0x80000000u);
}

// ---------- 1. fused copy + score ----------
__global__ __launch_bounds__(256) void score_copy_kernel(
    const float* __restrict__ roi, const float* __restrict__ wsc,
    const float* __restrict__ bsc, float* __restrict__ out,
    float* __restrict__ scores) {
  const int w = threadIdx.x >> 6, lane = threadIdx.x & 63;
  const int row = blockIdx.x * 4 + w;
  const float4* r4 = (const float4*)(roi + (size_t)row * DIM);
  const float4* w4 = (const float4*)wsc;
  float4* o4 = (float4*)(out + (size_t)row * DIM);
  float sum = 0.f;
#pragma unroll
  for (int rep = 0; rep < 4; ++rep) {
    int i = rep * 64 + lane;
    float4 v = r4[i];
    float4 q = w4[i];
    sum += v.x * q.x + v.y * q.y + v.z * q.z + v.w * q.w;
    o4[i] = v;
  }
#pragma unroll
  for (int d = 1; d < 64; d <<= 1) sum += __shfl_xor(sum, d);
  if (lane == 0) scores[row] = sum + bsc[0];
}

// ---------- 2. f32 -> bf16 convert (all four weights in one launch) ----------
__global__ __launch_bounds__(256) void cvt4_kernel(
    const float* __restrict__ wq, const float* __restrict__ wk,
    const float* __restrict__ wv, const float* __restrict__ wo,
    u16* __restrict__ wqb, u16* __restrict__ wkb,
    u16* __restrict__ wvb, u16* __restrict__ wob) {
  const int M = DIM * DIM;  // 1M elements per QKV weight
  long long i = ((long long)blockIdx.x * 256 + threadIdx.x) * 4;
  const float* src;
  u16* dst;
  if (i < M) {
    src = wq; dst = wqb;
  } else if (i < 2LL * M) {
    src = wk; dst = wkb; i -= M;
  } else if (i < 3LL * M) {
    src = wv; dst = wvb; i -= 2LL * M;
  } else {
    src = wo; dst = wob; i -= 3LL * M;
  }
  float4 v = *(const float4*)(src + i);
  ushort4 o = make_ushort4(f2bf(v.x), f2bf(v.y), f2bf(v.z), f2bf(v.w));
  *(ushort4*)(dst + i) = o;
}

// ---------- 3. single-block radix-select top-K (parallel suffix scan) ----------
// 3 passes over bit-fields [31:21], [20:10], [9:0]; keys register-cached.
__global__ __launch_bounds__(1024) void topk_kernel(const float* __restrict__ scores,
                                                    int* __restrict__ out_idx) {
  __shared__ u32 hist[2048];
  __shared__ int sneed;
  __shared__ u32 sbucket;
  __shared__ int scan_gt[1024];
  __shared__ int scan_eq[1024];
  const int tid = threadIdx.x;

  // load + monotone-transform this thread's 32 contiguous keys once
  u32 keys[32];
  const float4* sp = (const float4*)(scores + (size_t)tid * 32);
#pragma unroll
  for (int j = 0; j < 8; ++j) {
    float4 v = sp[j];
    keys[j * 4 + 0] = mono(v.x);
    keys[j * 4 + 1] = mono(v.y);
    keys[j * 4 + 2] = mono(v.z);
    keys[j * 4 + 3] = mono(v.w);
  }
  if (tid == 0) sneed = KSEL;

  u32 pref = 0;
  const int shifts[3] = {21, 10, 0};
#pragma unroll
  for (int pass = 0; pass < 3; ++pass) {
    const int shift = shifts[pass];
    hist[tid] = 0u;
    hist[tid + 1024] = 0u;
    __syncthreads();
    const u32 prefmask = (pass == 0) ? 0u : (0xFFFFFFFFu << shifts[pass - 1]);
#pragma unroll
    for (int j = 0; j < 32; ++j) {
      u32 k = keys[j];
      if ((k & prefmask) == pref) atomicAdd(&hist[(k >> shift) & 2047u], 1u);
    }
    __syncthreads();
    // parallel inclusive suffix sum over 2048 buckets (Hillis-Steele, 2/thread)
    for (int off = 1; off < 2048; off <<= 1) {
      u32 v0 = (tid + off < 2048) ? hist[tid + off] : 0u;
      u32 v1 = (tid + 1024 + off < 2048) ? hist[tid + 1024 + off] : 0u;
      __syncthreads();
      hist[tid] += v0;
      hist[tid + 1024] += v1;
      __syncthreads();
    }
    const int need = sneed;   // stable: last write was >=2 barriers ago
    __syncthreads();
    // largest bucket b with suffix_count(b) >= need  (unique crossing point)
#pragma unroll
    for (int e = 0; e < 2; ++e) {
      const int i = tid + e * 1024;
      const int s = (int)hist[i];
      const int snx = (i < 2047) ? (int)hist[i + 1] : 0;
      if (s >= need && snx < need) {
        sbucket = (u32)i;
        sneed = need - snx;
      }
    }
    __syncthreads();
    pref |= (sbucket << shift);
  }
  const u32 T = pref;

  // stable compaction: thread t owns contiguous indices [t*32, t*32+32)
  const int base = tid * 32;
  int cgt = 0, ceq = 0;
#pragma unroll
  for (int j = 0; j < 32; ++j) {
    cgt += (keys[j] > T);
    ceq += (keys[j] == T);
  }
  scan_gt[tid] = cgt;
  scan_eq[tid] = ceq;
  __syncthreads();
  for (int off = 1; off < 1024; off <<= 1) {
    int a = (tid >= off) ? scan_gt[tid - off] : 0;
    int b = (tid >= off) ? scan_eq[tid - off] : 0;
    __syncthreads();
    scan_gt[tid] += a;
    scan_eq[tid] += b;
    __syncthreads();
  }
  const int gt_off = scan_gt[tid] - cgt;
  const int eq_off = scan_eq[tid] - ceq;
  const int total_gt = scan_gt[1023];
  int g = gt_off, e = eq_off;
#pragma unroll
  for (int j = 0; j < 32; ++j) {
    u32 key = keys[j];
    if (key > T) {
      out_idx[g++] = base + j;
    } else if (key == T) {
      if (total_gt + e < KSEL) out_idx[total_gt + e] = base + j;  // lowest-index ties, jax-style
      e++;
    }
  }
}

// ---------- 4. gather selected rows -> xo[:,1024:2048] (bf16) ----------
__global__ __launch_bounds__(256) void gather_kernel(const float* __restrict__ out,
                                                     const int* __restrict__ idx,
                                                     u16* __restrict__ xo) {
  const int j = blockIdx.x;
  const int row = idx[j];
  const int c = threadIdx.x * 4;
  float4 v = *(const float4*)(out + (size_t)row * DIM + c);
  ushort4 o = make_ushort4(f2bf(v.x), f2bf(v.y), f2bf(v.z), f2bf(v.w));
  *(ushort4*)(xo + (size_t)j * 2048 + 1024 + c) = o;
}

// ---------- 5. GEMM  C[M,N] = A[M,Kd] @ W[N,Kd]^T + bias ----------
// 64x64 tile / block of 256 (4 waves, each 16 rows x 64 cols). bf16 MFMA 16x16x32.
// OUT_MODE: 0 = bf16 row-major, 1 = f32 row-major, 2 = bf16 transposed head-planar [h][hd][key]
template <int OUT_MODE>
__global__ __launch_bounds__(256) void gemm_xwt_kernel(
    const u16* __restrict__ A, int lda, const u16* __restrict__ W, int ldw,
    const float* __restrict__ bias, void* __restrict__ Cout, int ldc, int Kd) {
  __shared__ __align__(16) u16 As[64][40];  // +8 pad: ds_read_b128 2-way only
  __shared__ __align__(16) u16 Bs[64][40];
  const int m0 = blockIdx.y * 64, n0 = blockIdx.x * 64;
  const int w = threadIdx.x >> 6, lane = threadIdx.x & 63;
  const int t = lane & 15, quad = lane >> 4;
  const int srow = threadIdx.x >> 2, skc = (threadIdx.x & 3) * 8;
  v4f acc[4];
#pragma unroll
  for (int i = 0; i < 4; ++i) acc[i] = (v4f){0.f, 0.f, 0.f, 0.f};
  const u16* aptr = A + (size_t)(m0 + srow) * lda + skc;
  const u16* bptr = W + (size_t)(n0 + srow) * ldw + skc;
  uint4 areg = *(const uint4*)aptr;
  uint4 breg = *(const uint4*)bptr;
  for (int k0 = 0; k0 < Kd; k0 += 32) {
    __syncthreads();
    *(uint4*)&As[srow][skc] = areg;
    *(uint4*)&Bs[srow][skc] = breg;
    __syncthreads();
    const int kn = (k0 + 32 < Kd) ? k0 + 32 : 0;  // wrap: harmless reload, keeps loads uniform
    areg = *(const uint4*)(aptr + kn);
    breg = *(const uint4*)(bptr + kn);
    v8s af = *(const v8s*)&As[w * 16 + t][quad * 8];
#pragma unroll
    for (int nc = 0; nc < 4; ++nc) {
      v8s bf = *(const v8s*)&Bs[nc * 16 + t][quad * 8];
      acc[nc] = __builtin_amdgcn_mfma_f32_16x16x32_bf16(af, bf, acc[nc], 0, 0, 0);
    }
  }
#pragma unroll
  for (int nc = 0; nc < 4; ++nc) {
    const int col = n0 + nc * 16 + t;
    const float bv = bias[col];
    if (OUT_MODE == 2) {
      const int h = col >> 7, hd = col & 127;
      const int row0 = m0 + w * 16 + quad * 4;
      ushort4 pk = make_ushort4(f2bf(acc[nc][0] + bv), f2bf(acc[nc][1] + bv),
                                f2bf(acc[nc][2] + bv), f2bf(acc[nc][3] + bv));
      *(ushort4*)((u16*)Cout + (size_t)h * (HD * KSEL) + (size_t)hd * KSEL + row0) = pk;
    } else {
#pragma unroll
      for (int r = 0; r < 4; ++r) {
        const int row = m0 + w * 16 + quad * 4 + r;
        float v = acc[nc][r] + bv;
        if (OUT_MODE == 1)
          ((float*)Cout)[(size_t)row * ldc + col] = v;
        else
          ((u16*)Cout)[(size_t)row * ldc + col] = f2bf(v);
      }
    }
  }
}

// ---------- 6. per-(row,head) reciprocal norms of q and k ----------
__global__ __launch_bounds__(256) void norms_kernel(const u16* __restrict__ qb,
                                                    const u16* __restrict__ kb,
                                                    float* __restrict__ rnq,
                                                    float* __restrict__ rnk) {
  const int w = threadIdx.x >> 6, lane = threadIdx.x & 63;
  int p = blockIdx.x * 4 + w;
  const u16* src;
  float* dst;
  if (p < NHEAD * KSEL) {
    src = qb;
    dst = rnq;
  } else {
    src = kb;
    dst = rnk;
    p -= NHEAD * KSEL;
  }
  const int h = p >> 11, m = p & 2047;
  u32 u = *(const u32*)&src[(size_t)m * DIM + h * HD + lane * 2];
  float a = bf2f((u16)(u & 0xffffu)), b = bf2f((u16)(u >> 16));
  float ss = a * a + b * b;
#pragma unroll
  for (int d = 1; d < 64; d <<= 1) ss += __shfl_xor(ss, d);
  if (lane == 0) dst[h * KSEL + m] = 1.0f / (sqrtf(ss) + 1e-6f);
}

// ---------- 7. fused attention (static-max masked softmax) ----------
// grid: 8 heads * 32 q-blocks of 64 rows; block 256 = 4 waves, wave = 16 q rows.
// V supplied pre-transposed head-planar: vt[h][hd][key].
__global__ __launch_bounds__(256) void attn_kernel(
    const u16* __restrict__ qb, const u16* __restrict__ kb, const u16* __restrict__ vt,
    const float* __restrict__ rnq, const float* __restrict__ rnk,
    u16* __restrict__ xo) {
  const int h = blockIdx.x >> 5;
  const int q0 = (blockIdx.x & 31) * 64;
  const int tid = threadIdx.x;
  const int w = tid >> 6, lane = tid & 63;
  const int t = lane & 15, quad = lane >> 4;
  const int m0 = q0 + w * 16;

  __shared__ __align__(16) u16 Ks[32][136];   // [key][hd]
  __shared__ __align__(16) u16 Vs[128][40];   // [hd][key] (already transposed in global)
  __shared__ __align__(16) u16 Ps[4][16][40]; // per-wave P buffer
  __shared__ float rks[32];

  v8s qf[4];
#pragma unroll
  for (int c = 0; c < 4; ++c)
    qf[c] = *(const v8s*)&qb[(size_t)(m0 + t) * DIM + h * HD + c * 32 + quad * 8];
  float rq[4];
#pragma unroll
  for (int r = 0; r < 4; ++r) rq[r] = rnq[h * KSEL + m0 + quad * 4 + r];

  float li[4] = {0.f, 0.f, 0.f, 0.f};
  v4f o[8];
#pragma unroll
  for (int f = 0; f < 8; ++f) o[f] = (v4f){0.f, 0.f, 0.f, 0.f};

  const float scale = 0.08838834764831845f;  // 1/sqrt(128)

  // staging geometry
  const int kkey = tid >> 4;            // 0..15
  const int khc = (tid & 15) * 8;       // 0..120
  const int vhd = tid >> 2;             // 0..63
  const int vch = (tid & 3) * 8;        // 0..24
  const u16* kbase = kb + (size_t)h * HD + khc;
  const u16* vbase = vt + (size_t)h * (HD * KSEL) + (size_t)vhd * KSEL + vch;
  const float* rkb = rnk + h * KSEL + tid;

  uint4 kreg0, kreg1, vreg0, vreg1;
  float rkreg = 0.f;
#define PREFETCH(KT)                                                   \
  do {                                                                 \
    kreg0 = *(const uint4*)(kbase + (size_t)((KT) + kkey) * DIM);      \
    kreg1 = *(const uint4*)(kbase + (size_t)((KT) + kkey + 16) * DIM); \
    vreg0 = *(const uint4*)(vbase + (KT));                             \
    vreg1 = *(const uint4*)(vbase + (size_t)64 * KSEL + (KT));         \
    if (tid < 32) rkreg = rkb[(KT)];                                   \
  } while (0)

  PREFETCH(0);
  for (int kt = 0; kt < KSEL; kt += 32) {
    __syncthreads();
    *(uint4*)&Ks[kkey][khc] = kreg0;
    *(uint4*)&Ks[kkey + 16][khc] = kreg1;
    *(uint4*)&Vs[vhd][vch] = vreg0;
    *(uint4*)&Vs[vhd + 64][vch] = vreg1;
    if (tid < 32) rks[tid] = rkreg;
    __syncthreads();
    const int ktn = (kt + 32 < KSEL) ? kt + 32 : 0;
    PREFETCH(ktn);

    // S = q . k  (shared by logits and cosine-sim)
    v4f s0 = (v4f){0.f, 0.f, 0.f, 0.f}, s1 = (v4f){0.f, 0.f, 0.f, 0.f};
#pragma unroll
    for (int c = 0; c < 4; ++c) {
      v8s k0f = *(const v8s*)&Ks[t][c * 32 + quad * 8];
      v8s k1f = *(const v8s*)&Ks[16 + t][c * 32 + quad * 8];
      s0 = __builtin_amdgcn_mfma_f32_16x16x32_bf16(qf[c], k0f, s0, 0, 0, 0);
      s1 = __builtin_amdgcn_mfma_f32_16x16x32_bf16(qf[c], k1f, s1, 0, 0, 0);
    }
    const float rk0 = rks[t], rk1 = rks[16 + t];
#pragma unroll
    for (int r = 0; r < 4; ++r) {
      const float S0 = s0[r], S1 = s1[r];
      // valid => sim>0.9 => S>0 => p>=1; masked p is exactly 0
      const float p0 = (S0 * rq[r] * rk0 > 0.9f) ? __expf(S0 * scale) : 0.f;
      const float p1 = (S1 * rq[r] * rk1 > 0.9f) ? __expf(S1 * scale) : 0.f;
      li[r] += p0 + p1;  // per-lane partial; reduced over t-lanes once at the end
      Ps[w][quad * 4 + r][t] = f2bf(p0);
      Ps[w][quad * 4 + r][16 + t] = f2bf(p1);
    }
    // per-wave LDS roundtrip (C-layout -> A-layout); DS ops in-order within a wave
    v8s pf = *(const v8s*)&Ps[w][t][quad * 8];
#pragma unroll
    for (int f = 0; f < 8; ++f) {
      v8s vf = *(const v8s*)&Vs[f * 16 + t][quad * 8];
      o[f] = __builtin_amdgcn_mfma_f32_16x16x32_bf16(pf, vf, o[f], 0, 0, 0);
    }
  }
#undef PREFETCH
  float inv[4];
#pragma unroll
  for (int r = 0; r < 4; ++r) {
    float l = li[r];
    l += __shfl_xor(l, 1);
    l += __shfl_xor(l, 2);
    l += __shfl_xor(l, 4);
    l += __shfl_xor(l, 8);
    inv[r] = (l > 0.f) ? 1.0f / l : 0.f;  // l==0 <=> no match (dropout-to-zero path)
  }
#pragma unroll
  for (int f = 0; f < 8; ++f)
#pragma unroll
    for (int r = 0; r < 4; ++r)
      xo[(size_t)(m0 + quad * 4 + r) * 2048 + h * HD + f * 16 + t] = f2bf(o[f][r] * inv[r]);
}

// ---------- 8. final scatter: out[idx[j]] = 0.5*sel + 0.5*fused ----------
__global__ __launch_bounds__(256) void final_kernel(float* __restrict__ out,
                                                    const int* __restrict__ idx,
                                                    const float* __restrict__ fused) {
  const int j = blockIdx.x;
  const int row = idx[j];
  const int c = threadIdx.x * 4;
  float4 a = *(const float4*)(out + (size_t)row * DIM + c);
  float4 f = *(const float4*)(fused + (size_t)j * DIM + c);
  float4 rv;
  rv.x = 0.5f * (a.x + f.x);
  rv.y = 0.5f * (a.y + f.y);
  rv.z = 0.5f * (a.z + f.z);
  rv.w = 0.5f * (a.w + f.w);
  *(float4*)(out + (size_t)row * DIM + c) = rv;
}

// ---------- launch ----------
extern "C" void kernel_launch(void* const* d_in, const int* in_sizes, int n_in,
                              void* d_out, int out_size, void* d_ws, size_t ws_size,
                              hipStream_t stream) {
  const float* roi = (const float*)d_in[0];
  const float* w_score = (const float*)d_in[1];
  const float* b_score = (const float*)d_in[2];
  const float* wq = (const float*)d_in[3];
  const float* bq = (const float*)d_in[4];
  const float* wk = (const float*)d_in[5];
  const float* bk = (const float*)d_in[6];
  const float* wv = (const float*)d_in[7];
  const float* bv = (const float*)d_in[8];
  const float* wo = (const float*)d_in[9];
  const float* bo = (const float*)d_in[10];
  float* out = (float*)d_out;

  char* p = (char*)d_ws;
  auto alloc = [&](size_t bytes) {
    char* r = p;
    p += (bytes + 255) & ~(size_t)255;
    return r;
  };
  float* scores = (float*)alloc((size_t)N_ROWS * 4);
  int* topk = (int*)alloc((size_t)KSEL * 4);
  u16* wqb = (u16*)alloc((size_t)DIM * DIM * 2);
  u16* wkb = (u16*)alloc((size_t)DIM * DIM * 2);
  u16* wvb = (u16*)alloc((size_t)DIM * DIM * 2);
  u16* wob = (u16*)alloc((size_t)DIM * 2 * DIM * 2);
  u16* xo = (u16*)alloc((size_t)KSEL * 2048 * 2);  // [agg | dst] bf16
  u16* qbuf = (u16*)alloc((size_t)KSEL * DIM * 2);
  u16* kbuf = (u16*)alloc((size_t)KSEL * DIM * 2);
  u16* vtbuf = (u16*)alloc((size_t)KSEL * DIM * 2);  // [h][hd][key]
  float* rnq = (float*)alloc((size_t)NHEAD * KSEL * 4);
  float* rnk = (float*)alloc((size_t)NHEAD * KSEL * 4);
  float* fused = (float*)alloc((size_t)KSEL * DIM * 4);

  score_copy_kernel<<<N_ROWS / 4, 256, 0, stream>>>(roi, w_score, b_score, out, scores);
  cvt4_kernel<<<5 * DIM * DIM / 1024, 256, 0, stream>>>(wq, wk, wv, wo, wqb, wkb, wvb, wob);
  topk_kernel<<<1, 1024, 0, stream>>>(scores, topk);
  gather_kernel<<<KSEL, 256, 0, stream>>>(out, topk, xo);
  gemm_xwt_kernel<0><<<dim3(16, 32), 256, 0, stream>>>(xo + 1024, 2048, wqb, DIM, bq, qbuf, DIM, DIM);
  gemm_xwt_kernel<0><<<dim3(16, 32), 256, 0, stream>>>(xo + 1024, 2048, wkb, DIM, bk, kbuf, DIM, DIM);
  gemm_xwt_kernel<2><<<dim3(16, 32), 256, 0, stream>>>(xo + 1024, 2048, wvb, DIM, bv, vtbuf, DIM, DIM);
  norms_kernel<<<2 * NHEAD * KSEL / 4, 256, 0, stream>>>(qbuf, kbuf, rnq, rnk);
  attn_kernel<<<NHEAD * 32, 256, 0, stream>>>(qbuf, kbuf, vtbuf, rnq, rnk, xo);
  gemm_xwt_kernel<1><<<dim3(16, 32), 256, 0, stream>>>(xo, 2048, wob, 2048, bo, fused, DIM, 2048);
  final_kernel<<<KSEL, 256, 0, stream>>>(out, topk, fused);
}